// Round 8
// baseline (661.293 us; speedup 1.0000x reference)
//
#include <hip/hip_runtime.h>
#include <math.h>

// Problem constants
// x: (B=2, C=32, D=96, H=96, W=96) fp32
// out: (2, 32, 48, 48, 48) fp32
#define HS 0.35355339059327373f   /* 1/(2*sqrt(2)) — 3-stage Haar scale */
#define NSPAT 110592              /* 48^3 */
#define NBN   221184              /* B * 48^3 */

// ---------------------------------------------------------------------------
// K1: per-(b,c) parity sums S[b][c][p][q][r] = sum over x[2i+p][2j+q][2l+r]
// One block per (b,c,d)-plane. Memory-bound (226 MB @ ~5.6 TB/s ≈ 40 µs).
// ---------------------------------------------------------------------------
__global__ __launch_bounds__(256) void k1_parity(const float* __restrict__ x,
                                                 float* __restrict__ S) {
    int blk = blockIdx.x;            // (b*32+c)*96 + d
    int d   = blk % 96;
    int bc  = blk / 96;
    const float4* x4 = (const float4*)x + (long)blk * 2304;
    int tid = threadIdx.x;
    float aE0 = 0.f, aO0 = 0.f, aE1 = 0.f, aO1 = 0.f;  // [q][r]
#pragma unroll
    for (int i = 0; i < 9; ++i) {
        int f = tid + i * 256;           // < 2304
        float4 v = x4[f];
        int h = f / 24;                  // row within plane
        float e = v.x + v.z, o = v.y + v.w;
        if (h & 1) { aE1 += e; aO1 += o; }
        else       { aE0 += e; aO0 += o; }
    }
#pragma unroll
    for (int m = 32; m; m >>= 1) {
        aE0 += __shfl_xor(aE0, m, 64); aO0 += __shfl_xor(aO0, m, 64);
        aE1 += __shfl_xor(aE1, m, 64); aO1 += __shfl_xor(aO1, m, 64);
    }
    __shared__ float red[4][4];
    int lane = tid & 63, wave = tid >> 6;
    if (lane == 0) { red[wave][0] = aE0; red[wave][1] = aO0;
                     red[wave][2] = aE1; red[wave][3] = aO1; }
    __syncthreads();
    if (tid < 4) {
        float v = red[0][tid] + red[1][tid] + red[2][tid] + red[3][tid];
        int q = tid >> 1, r = tid & 1, p = d & 1;
        atomicAdd(&S[bc * 8 + p * 4 + q * 2 + r], v);
    }
}

// ---------------------------------------------------------------------------
// K2 (tiny): band means -> two attention MLPs -> effective fuse matrix.
// Layout: A[b][og(4)][c(32)][o'(8)][pqr(8)] — per-(og,c) slice is 64
// contiguous floats (k3 wave og reads it via scalar pipe).
// ---------------------------------------------------------------------------
__global__ __launch_bounds__(256) void k2_attn(
        const float* __restrict__ S,
        const float* __restrict__ w1l, const float* __restrict__ w2l,
        const float* __restrict__ w1h, const float* __restrict__ w2h,
        const float* __restrict__ wf, float* __restrict__ A) {
    int b = blockIdx.x, tid = threadIdx.x;
    __shared__ float mlow[32], mhigh[224], h1l[2], h1h[14], ylow[32], yhigh[224];
    const float* Sb = S + b * 256;
    const float MS = HS / (float)NSPAT;   // subband mean scale
    if (tid < 32) {
        float s = 0.f;
        for (int j = 0; j < 8; ++j) s += Sb[tid * 8 + j];
        mlow[tid] = s * MS;
    }
    if (tid < 224) {
        int c = tid / 7, k = tid % 7, dm = k + 1;
        float s = 0.f;
        for (int j = 0; j < 8; ++j) {
            float sg = (__popc(j & dm) & 1) ? -1.f : 1.f;
            s += sg * Sb[c * 8 + j];
        }
        mhigh[tid] = s * MS;
    }
    __syncthreads();
    if (tid < 2) {
        float s = 0.f;
        for (int c = 0; c < 32; ++c) s += w1l[tid * 32 + c] * mlow[c];
        h1l[tid] = fmaxf(s, 0.f);
    } else if (tid < 16) {
        int j = tid - 2;
        float s = 0.f;
        for (int c = 0; c < 224; ++c) s += w1h[j * 224 + c] * mhigh[c];
        h1h[j] = fmaxf(s, 0.f);
    }
    __syncthreads();
    if (tid < 32) {
        float s = w2l[tid * 2] * h1l[0] + w2l[tid * 2 + 1] * h1l[1];
        ylow[tid] = 1.f / (1.f + expf(-s));
    } else if (tid < 256) {
        int i = tid - 32;
        float s = 0.f;
        for (int j = 0; j < 14; ++j) s += w2h[i * 14 + j] * h1h[j];
        yhigh[i] = 1.f / (1.f + expf(-s));
    }
    __syncthreads();
    for (int idx = tid; idx < 8192; idx += 256) {
        int o = idx >> 8, c = (idx >> 3) & 31, pqr = idx & 7;
        float a = wf[o * 256 + c] * ylow[c];
#pragma unroll
        for (int k = 0; k < 7; ++k) {
            float sg = (__popc(pqr & (k + 1)) & 1) ? -1.f : 1.f;
            a += sg * wf[o * 256 + 32 + c * 7 + k] * yhigh[c * 7 + k];
        }
        int og = o >> 3, op = o & 7;
        A[b * 8192 + og * 2048 + c * 64 + op * 8 + pqr] = a * HS;
    }
}

// ---------------------------------------------------------------------------
// K3 (main): z[b,o,od,oh,ow] = sum_{c,pqr} A[...] * x[b,c,2od+p,2oh+q,2ow+r]
// R8: LDS-staged x — the only sharing mechanism that works (R4/R6/R7 showed
// cache-mediated sharing fails: cross-block -> HBM re-fetch, cross-wave L1
// -> thrash at 32 waves/CU).
//  - Block = 4 waves over ONE 64-voxel tile. Wave wv stages parity
//    (p,q)=wv of an 8-c chunk: 1 float2 global load per lane per c
//    (x partitioned EXACTLY once across the grid -> 226 MB HBM total),
//    double-buffered 2 x 16 KB LDS.
//  - Compute: wave wv does o in [8wv, 8wv+8) for all c. Per c: 4
//    ds_read_b64 (lanes consecutive -> 2-way alias = free) + 64 FMAs.
//    A = 64 floats/c/wave via block-uniform scalar loads (R6-proven).
//  - Per-thread: 8 acc + 16 staging + 8 lds regs ~ 52 VGPR; LDS 32 KB ->
//    5 blocks/CU = 20 waves/CU; 8 staging loads in flight/thread.
// Grid 3456 = b(2) x od(48) x vblk(36).
// BN: per-wave butterfly, lane0 atomics into 16 replica lines.
// ---------------------------------------------------------------------------
__global__ __launch_bounds__(256) void k3_main(const float* __restrict__ x,
                                               const float* __restrict__ A,
                                               float* __restrict__ z,
                                               float* __restrict__ bnRep) {
    __shared__ float2 buf[2][8][4][64];     // [dbuf][c-in-chunk][pq][vox] 32 KB
    int blk  = blockIdx.x;                  // (b*48+od)*36 + vblk
    int vblk = blk % 36;
    int tmp  = blk / 36;
    int od   = tmp % 48;
    int b    = tmp / 48;
    int tid  = threadIdx.x;
    int lane = tid & 63;
    int wv   = __builtin_amdgcn_readfirstlane(tid >> 6);  // o-group & (p,q) role
    int v    = vblk * 64 + lane;
    int oh   = v / 48, ow = v % 48;

    // staging address: (p,q) = (wv>>1, wv&1)
    int p = wv >> 1, q = wv & 1;
    const float2* x2 = (const float2*)x;
    // float2 idx = (b*32+c)*442368 + (2od+p)*4608 + (2oh+q)*48 + ow
    int gbase = (b * 32) * 442368 + (2 * od + p) * 4608 + (2 * oh + q) * 48 + ow;

    const float* Ab = A + b * 8192 + wv * 2048;   // [c<32][o'<8][pqr<8], uniform

    float acc[8];
#pragma unroll
    for (int o = 0; o < 8; ++o) acc[o] = 0.f;

    float2 st[8];
    // prologue: stage chunk 0
#pragma unroll
    for (int i = 0; i < 8; ++i) st[i] = x2[gbase + i * 442368];
#pragma unroll
    for (int i = 0; i < 8; ++i) buf[0][i][wv][lane] = st[i];
    __syncthreads();

    for (int cc = 0; cc < 4; ++cc) {
        if (cc < 3) {
#pragma unroll
            for (int i = 0; i < 8; ++i)
                st[i] = x2[gbase + ((cc + 1) * 8 + i) * 442368];
        }
#pragma unroll
        for (int i = 0; i < 8; ++i) {
            float2 v00 = buf[cc & 1][i][0][lane];
            float2 v01 = buf[cc & 1][i][1][lane];
            float2 v10 = buf[cc & 1][i][2][lane];
            float2 v11 = buf[cc & 1][i][3][lane];
            const float* Ac = Ab + (cc * 8 + i) * 64;
#pragma unroll
            for (int o = 0; o < 8; ++o) {
                const float* Ao = Ac + o * 8;         // uniform -> SGPRs
                acc[o] += Ao[0] * v00.x + Ao[1] * v00.y + Ao[2] * v01.x + Ao[3] * v01.y
                        + Ao[4] * v10.x + Ao[5] * v10.y + Ao[6] * v11.x + Ao[7] * v11.y;
            }
        }
        if (cc < 3) {
            __syncthreads();   // all waves done reading buf[(cc+1)&1] (iter cc-1)
#pragma unroll
            for (int i = 0; i < 8; ++i) buf[(cc + 1) & 1][i][wv][lane] = st[i];
            __syncthreads();
        }
    }

    // z stores: per o, 64 lanes cover 64 consecutive voxels -> coalesced b32
#pragma unroll
    for (int o = 0; o < 8; ++o) {
        z[((b * 32 + wv * 8 + o) * 48 + od) * 2304 + v] = acc[o];
    }

    // BN partials: butterfly per o, lane0 atomics (16 replica lines)
    int rep = (blockIdx.x & 15) * 64;
#pragma unroll
    for (int o = 0; o < 8; ++o) {
        float sv = acc[o];
        float qv = acc[o] * acc[o];
#pragma unroll
        for (int m = 32; m; m >>= 1) {
            sv += __shfl_xor(sv, m, 64);
            qv += __shfl_xor(qv, m, 64);
        }
        if (lane == 0) {
            atomicAdd(&bnRep[rep + wv * 8 + o], sv);
            atomicAdd(&bnRep[rep + 32 + wv * 8 + o], qv);
        }
    }
}

// ---------------------------------------------------------------------------
// K5: BN finalize (sum 16 replicas, per-block recompute) + normalize + ReLU,
// in place over z (= d_out). 1769472 float4s. b_fuse cancels under BN.
// ---------------------------------------------------------------------------
__global__ __launch_bounds__(256) void k5_norm(float* __restrict__ z,
                                               const float* __restrict__ bnRep,
                                               const float* __restrict__ gamma,
                                               const float* __restrict__ beta) {
    __shared__ float s_sc[32], s_sh[32];
    int tid = threadIdx.x;
    if (tid < 32) {
        float s = 0.f, q = 0.f;
#pragma unroll
        for (int r = 0; r < 16; ++r) {
            s += bnRep[r * 64 + tid];
            q += bnRep[r * 64 + 32 + tid];
        }
        const float invN = 1.f / (float)NBN;
        float mean = s * invN;
        float var  = q * invN - mean * mean;
        float inv  = rsqrtf(var + 1e-5f);
        float sc   = gamma[tid] * inv;
        s_sc[tid] = sc;
        s_sh[tid] = beta[tid] - mean * sc;
    }
    int i = blockIdx.x * 256 + tid;                // float4 index
    float4* z4 = (float4*)z;
    float4 v = z4[i];                              // load before barrier (indep)
    __syncthreads();
    int o = (i / 27648) & 31;                      // 27648 = 48^3/4
    float sc = s_sc[o], sh = s_sh[o];
    v.x = fmaxf(v.x * sc + sh, 0.f);
    v.y = fmaxf(v.y * sc + sh, 0.f);
    v.z = fmaxf(v.z * sc + sh, 0.f);
    v.w = fmaxf(v.w * sc + sh, 0.f);
    z4[i] = v;
}

extern "C" void kernel_launch(void* const* d_in, const int* in_sizes, int n_in,
                              void* d_out, int out_size, void* d_ws, size_t ws_size,
                              hipStream_t stream) {
    const float* x    = (const float*)d_in[0];
    const float* w1l  = (const float*)d_in[1];
    const float* w2l  = (const float*)d_in[2];
    const float* w1h  = (const float*)d_in[3];
    const float* w2h  = (const float*)d_in[4];
    const float* wf   = (const float*)d_in[5];
    // d_in[6] = b_fuse: cancels exactly under training-mode BN (mean subtract)
    const float* gamma = (const float*)d_in[7];
    const float* beta  = (const float*)d_in[8];
    float* out = (float*)d_out;

    float* ws    = (float*)d_ws;
    float* S     = ws;          // 512 floats (zeroed)
    float* bnRep = ws + 512;    // 16 x (32 sum + 32 sq) = 1024 floats (zeroed)
    float* A     = ws + 2048;   // 16384 floats

    hipMemsetAsync(d_ws, 0, 1536 * sizeof(float), stream);
    k1_parity<<<6144, 256, 0, stream>>>(x, S);
    k2_attn<<<2, 256, 0, stream>>>(S, w1l, w2l, w1h, w2h, wf, A);
    k3_main<<<3456, 256, 0, stream>>>(x, A, out, bnRep);
    k5_norm<<<6912, 256, 0, stream>>>(out, bnRep, gamma, beta);
}